// Round 5
// baseline (421.242 us; speedup 1.0000x reference)
//
#include <hip/hip_runtime.h>
#include <cstddef>
#include <cstdint>

// Problem constants (fixed by setup_inputs)
#define B_  4
#define L_  1024
#define H_  8
#define DK_ 32
#define DV_ 32
#define BH_ 32            // B_*H_
#define HD_ 256           // H_*DK_

#define INV_T 0.17677669529663687f  // 1/sqrt(32)

// async global->LDS DMA, 16 bytes per lane (dest = wave-uniform base + lane*16)
__device__ __forceinline__ void gload_lds16(const void* g, void* l) {
    __builtin_amdgcn_global_load_lds(
        (const __attribute__((address_space(1))) void*)g,
        (__attribute__((address_space(3))) void*)l,
        16, 0, 0);
}

// ---------------------------------------------------------------------------
// Kernel 0: transpose q[b, j, h*32+d] -> qT[bh][d4][j][c]  (c = d%4)
// grid 128 = bh(32) x jt(4), 256 threads
// ---------------------------------------------------------------------------
__global__ __launch_bounds__(256) void transpose_q(
    const float* __restrict__ q, float* __restrict__ qT)
{
    const int bh  = blockIdx.x >> 2;
    const int jt  = blockIdx.x & 3;
    const int b   = bh >> 3, h = bh & 7;
    const int tid = threadIdx.x;

    __shared__ float t_s[256][33];

    const float* qb = q + (size_t)b * L_ * HD_ + h * DK_;
    #pragma unroll
    for (int rep = 0; rep < 8; ++rep) {
        const int f = rep * 1024 + tid * 4;
        const int j = f >> 5, d = f & 31;
        float4 val = *reinterpret_cast<const float4*>(qb + (size_t)(jt * 256 + j) * HD_ + d);
        t_s[j][d + 0] = val.x; t_s[j][d + 1] = val.y;
        t_s[j][d + 2] = val.z; t_s[j][d + 3] = val.w;
    }
    __syncthreads();
    float* qo = qT + (size_t)bh * (DK_ * L_);
    const int j = jt * 256 + tid;
    #pragma unroll
    for (int d4 = 0; d4 < 8; ++d4) {
        float4 w = make_float4(t_s[tid][d4 * 4 + 0], t_s[tid][d4 * 4 + 1],
                               t_s[tid][d4 * 4 + 2], t_s[tid][d4 * 4 + 3]);
        *reinterpret_cast<float4*>(qo + (size_t)d4 * (L_ * 4) + (size_t)j * 4) = w;
    }
}

// ---------------------------------------------------------------------------
// Kernel 1: scores. grid 2048 = ig(512: 2 i-rows) x half(2) x jhalf(2).
// a_k staged via global_load_lds into a double-buffered, XOR-swizzled LDS
// tile; ONE vmcnt(0)+barrier per jt; next tile's DMA in flight across the
// whole compute phase (T3 minimum 2-phase template).
// LDS layout [buf][ii][jj][d] linear; chunk c (16B) holds global chunk
// c ^ (jj&7)  (pre-swizzled source, swizzled read: both-sides).
// ---------------------------------------------------------------------------
__global__ __launch_bounds__(256) void score_kernel(
    const float* __restrict__ qT,
    const float* __restrict__ k,
    const float* __restrict__ a_k,
    float* __restrict__ attn_u,
    float* __restrict__ sums)   // [2][BH_][L_] partials
{
    const int bidx  = blockIdx.x;
    const int jhalf = bidx & 1;
    const int half  = (bidx >> 1) & 1;
    const int ig    = bidx >> 2;          // 0..511
    const int i0    = ig * 2;
    const int bh0   = half * 16;
    const int tid   = threadIdx.x;
    const int w     = __builtin_amdgcn_readfirstlane(tid >> 6);  // wave-uniform
    const int lane  = tid & 63;

    __shared__ __align__(16) float a_s[2][2][64][32];   // 2 x 16 KB

    // staging decode (constant per thread): rep r covers lds bytes r*4096+tid*16
    int s_ii[4], s_jj[4], s_c[4];
    #pragma unroll
    for (int r2 = 0; r2 < 4; ++r2) {
        const int off = r2 * 4096 + tid * 16;
        s_ii[r2] = off >> 13;
        s_jj[r2] = (off >> 7) & 63;
        s_c[r2]  = ((off >> 4) & 7) ^ (s_jj[r2] & 7);   // pre-swizzled source chunk
    }

    auto STAGE = [&](int buf, int j0s) {
        #pragma unroll
        for (int r2 = 0; r2 < 4; ++r2) {
            const float* src = a_k + (size_t)(i0 + s_ii[r2]) * (L_ * DK_)
                             + (size_t)(j0s + s_jj[r2]) * DK_ + s_c[r2] * 4;
            float* dst = (float*)((char*)(&a_s[buf][0][0][0]) + r2 * 4096 + w * 1024);
            gload_lds16(src, dst);
        }
    };

    float rs[4][2] = {{0.f}};          // [bhl][ii] row-sum partials
    const int jt0 = jhalf * 8, jtE = jt0 + 8;
    int cur = 0;

    STAGE(0, jt0 * 64);
    asm volatile("s_waitcnt vmcnt(0)" ::: "memory");
    __builtin_amdgcn_s_barrier();

    for (int jt = jt0; jt < jtE; ++jt) {
        const int j0   = jt * 64;
        const bool more = (jt != jtE - 1);

        if (more) STAGE(cur ^ 1, j0 + 64);   // DMA next tile into other buffer

        float s[4][2];
        #pragma unroll
        for (int bhl = 0; bhl < 4; ++bhl)
            #pragma unroll
            for (int ii = 0; ii < 2; ++ii) s[bhl][ii] = 0.f;

        #pragma unroll 2
        for (int d4 = 0; d4 < 8; ++d4) {
            float4 av[2];
            #pragma unroll
            for (int ii = 0; ii < 2; ++ii)
                av[ii] = *reinterpret_cast<const float4*>(
                    (const char*)(&a_s[cur][ii][0][0]) + lane * 128
                    + ((d4 ^ (lane & 7)) << 4));        // swizzled read
            #pragma unroll
            for (int bhl = 0; bhl < 4; ++bhl) {
                const int bh = bh0 + w * 4 + bhl;      // wave-uniform
                const int b  = bh >> 3, h = bh & 7;
                const float4 q4 = *reinterpret_cast<const float4*>(
                    qT + (size_t)bh * (DK_ * L_) + (size_t)d4 * (L_ * 4) + (size_t)(j0 + lane) * 4);
                const float* kp = k + (size_t)b * L_ * HD_ + (size_t)i0 * HD_ + h * DK_ + d4 * 4;
                #pragma unroll
                for (int ii = 0; ii < 2; ++ii) {
                    float4 kv = *reinterpret_cast<const float4*>(kp + ii * HD_);  // s_load
                    s[bhl][ii] = fmaf(kv.x * av[ii].x, q4.x, s[bhl][ii]);
                    s[bhl][ii] = fmaf(kv.y * av[ii].y, q4.y, s[bhl][ii]);
                    s[bhl][ii] = fmaf(kv.z * av[ii].z, q4.z, s[bhl][ii]);
                    s[bhl][ii] = fmaf(kv.w * av[ii].w, q4.w, s[bhl][ii]);
                }
            }
        }

        #pragma unroll
        for (int bhl = 0; bhl < 4; ++bhl) {
            const int bh = bh0 + w * 4 + bhl;
            #pragma unroll
            for (int ii = 0; ii < 2; ++ii) {
                const float u = __expf(s[bhl][ii] * INV_T);
                rs[bhl][ii] += u;
                attn_u[((size_t)bh * L_ + (i0 + ii)) * L_ + j0 + lane] = u;
            }
        }

        if (more) {
            asm volatile("s_waitcnt vmcnt(0)" ::: "memory");  // prefetch landed
            __builtin_amdgcn_s_barrier();
            cur ^= 1;
        }
    }

    #pragma unroll
    for (int bhl = 0; bhl < 4; ++bhl) {
        #pragma unroll
        for (int ii = 0; ii < 2; ++ii) {
            float vsum = rs[bhl][ii];
            #pragma unroll
            for (int off = 32; off > 0; off >>= 1) vsum += __shfl_xor(vsum, off);
            if (lane == 0)
                sums[((size_t)jhalf * BH_ + bh0 + w * 4 + bhl) * L_ + i0 + ii] = vsum;
        }
    }
}

// ---------------------------------------------------------------------------
// Kernel 2: normalize + PV. grid 2048 = bh(32) x ic(64: 16 i-rows each).
// Same 2-phase gload_lds double-buffer. u staged RAW (swizzled chunks
// c^(rr&3)); PV accumulates raw u, scales by inv at the end; p written
// from an LDS re-read * inv.
// ---------------------------------------------------------------------------
__global__ __launch_bounds__(256) void pv_kernel(
    const float* __restrict__ v,
    const float* __restrict__ sums,
    float* __restrict__ attn,    // u on entry, p on exit
    float* __restrict__ out)
{
    const int bh  = blockIdx.x >> 6;
    const int ic  = blockIdx.x & 63;
    const int i0  = ic * 16;
    const int b   = bh >> 3, h = bh & 7;
    const int tid = threadIdx.x;
    const int w   = __builtin_amdgcn_readfirstlane(tid >> 6);
    const int r   = tid >> 4;          // 0..15 (own row: stage AND compute)
    const int t16 = tid & 15;

    __shared__ __align__(16) float v_s[2][64][32];   // 2 x 8 KB
    __shared__ __align__(16) float u_s[2][16][64];   // 2 x 4 KB

    const float inv = 1.0f / (sums[(size_t)bh * L_ + i0 + r] +
                              sums[(size_t)(BH_ + bh) * L_ + i0 + r]);
    float* arow = attn + ((size_t)bh * L_ + i0 + r) * L_;

    // u stage: thread covers lds byte tid*16; row rr = tid>>4 (== r),
    // chunk c = t16, source chunk c^(rr&3)
    const int u_c = t16 ^ (r & 3);
    const float* u_src0 = arow + u_c * 4;
    // v stage: rep s: off = s*4096 + tid*16 -> jj = s*32 + (tid>>3), dc = tid&7
    const float* vbase = v + (size_t)b * L_ * HD_ + h * DV_;
    const int v_jj0 = tid >> 3, v_dc = tid & 7;

    auto STAGE = [&](int buf, int j0s) {
        gload_lds16(u_src0 + j0s, (float*)((char*)(&u_s[buf][0][0]) + w * 1024));
        #pragma unroll
        for (int s2 = 0; s2 < 2; ++s2)
            gload_lds16(vbase + (size_t)(j0s + s2 * 32 + v_jj0) * HD_ + v_dc * 4,
                        (float*)((char*)(&v_s[buf][0][0]) + s2 * 4096 + w * 1024));
    };

    float a0 = 0.f, a1 = 0.f;
    int cur = 0;

    STAGE(0, 0);
    asm volatile("s_waitcnt vmcnt(0)" ::: "memory");
    __builtin_amdgcn_s_barrier();

    for (int jt = 0; jt < 16; ++jt) {
        const int j0   = jt * 64;
        const bool more = (jt != 15);

        if (more) STAGE(cur ^ 1, j0 + 64);

        // write p = u * inv (re-read own row, logical chunk t16)
        {
            const float4 uw = *reinterpret_cast<const float4*>(
                (const char*)(&u_s[cur][0][0]) + r * 256 + ((t16 ^ (r & 3)) << 4));
            float4 pw = make_float4(uw.x * inv, uw.y * inv, uw.z * inv, uw.w * inv);
            *reinterpret_cast<float4*>(arow + j0 + t16 * 4) = pw;
        }

        // acc += u[r][jj] * v[jj][dv]  (raw u; scale by inv at end)
        #pragma unroll
        for (int jj4 = 0; jj4 < 16; ++jj4) {
            const float4 u4 = *reinterpret_cast<const float4*>(
                (const char*)(&u_s[cur][0][0]) + r * 256 + ((jj4 ^ (r & 3)) << 4));
            const float2 vv0 = *reinterpret_cast<const float2*>(&v_s[cur][jj4 * 4 + 0][t16 * 2]);
            const float2 vv1 = *reinterpret_cast<const float2*>(&v_s[cur][jj4 * 4 + 1][t16 * 2]);
            const float2 vv2 = *reinterpret_cast<const float2*>(&v_s[cur][jj4 * 4 + 2][t16 * 2]);
            const float2 vv3 = *reinterpret_cast<const float2*>(&v_s[cur][jj4 * 4 + 3][t16 * 2]);
            a0 = fmaf(u4.x, vv0.x, a0); a1 = fmaf(u4.x, vv0.y, a1);
            a0 = fmaf(u4.y, vv1.x, a0); a1 = fmaf(u4.y, vv1.y, a1);
            a0 = fmaf(u4.z, vv2.x, a0); a1 = fmaf(u4.z, vv2.y, a1);
            a0 = fmaf(u4.w, vv3.x, a0); a1 = fmaf(u4.w, vv3.y, a1);
        }

        if (more) {
            asm volatile("s_waitcnt vmcnt(0)" ::: "memory");
            __builtin_amdgcn_s_barrier();
            cur ^= 1;
        }
    }

    *reinterpret_cast<float2*>(out + ((size_t)bh * L_ + i0 + r) * DV_ + t16 * 2)
        = make_float2(a0 * inv, a1 * inv);
}

extern "C" void kernel_launch(void* const* d_in, const int* in_sizes, int n_in,
                              void* d_out, int out_size, void* d_ws, size_t ws_size,
                              hipStream_t stream) {
    const float* q   = (const float*)d_in[0];
    const float* k   = (const float*)d_in[1];
    const float* v   = (const float*)d_in[2];
    const float* a_k = (const float*)d_in[3];

    float* out  = (float*)d_out;
    float* attn = out + (size_t)BH_ * L_ * DV_;   // out first, attn second

    float* ws   = (float*)d_ws;
    float* sums = ws;                        // 2*32*1024 floats = 256 KB
    float* qT   = ws + 2 * BH_ * L_;         // 4 MB

    transpose_q<<<dim3(128),   dim3(256), 0, stream>>>(q, qT);
    score_kernel<<<dim3(2048), dim3(256), 0, stream>>>(qT, k, a_k, attn, sums);
    pv_kernel<<<dim3(2048),    dim3(256), 0, stream>>>(v, sums, attn, out);
}